// Round 5
// baseline (100.626 us; speedup 1.0000x reference)
//
#include <hip/hip_runtime.h>
#include <math.h>

// Problem geometry
#define N_IMG   48          // B*C = 8*6
#define IMG_W   512
#define IMG_H   512
#define IMG_HW  (IMG_W*IMG_H)
#define OUT_W   506         // 512 - 6 (VALID 7x7)
#define OUT_H   506
#define BAND_H  23          // output rows per band; 23*22 = 506
#define N_BANDS 22
#define BAND_ROWS (BAND_H + 6)   // 29 staged input rows per band
#define HALF_COLS 253       // output columns per half-block
#define K1C     0.01f
#define K2C     0.03f

// ws layout (doubles first, then uints):
//   wsd[0..63]    = sum |diff| partial slots
//   wsd[64..127]  = sum diff^2 partial slots
//   wsd[128..223] = per-image SSIM sums (2 slots per image)
//   wsu (byte offset 1792): [0..47] per-image min (ordered-uint map),
//                           [48..95] per-image max
#define SLOT_S1   0
#define SLOT_S2   64
#define SLOT_SSIM 128
#define N_DBL     224
#define WSU_OFF   1792

__device__ __forceinline__ unsigned fmap(float f) {
  unsigned u = __float_as_uint(f);
  return (u & 0x80000000u) ? ~u : (u | 0x80000000u);
}
__device__ __forceinline__ float funmap(unsigned u) {
  return (u & 0x80000000u) ? __uint_as_float(u & 0x7FFFFFFFu)
                           : __uint_as_float(~u);
}

__global__ void init_ws(double* wsd, unsigned* wsu) {
  int t = threadIdx.x;
  if (t < N_DBL) wsd[t] = 0.0;
  if (t < 48) { wsu[t] = 0xFFFFFFFFu; wsu[48 + t] = 0u; }
}

// Pass 1: per-image min/max of y_true*mask ONLY (reads yt + mk, 100 MB).
// 64 chunks/image * 48 images = 3072 blocks, 256 threads, 4 float4/thread.
__global__ __launch_bounds__(256) void range_kernel(
    const float4* __restrict__ t4, const float4* __restrict__ m4,
    unsigned* __restrict__ wsu) {
  const int img = blockIdx.x >> 6;
  const int chunk = blockIdx.x & 63;
  const size_t base = (size_t)img * (IMG_HW / 4) + (size_t)chunk * (IMG_HW / 256);
  const int t = threadIdx.x;

  float mn = INFINITY, mx = -INFINITY;
#pragma unroll
  for (int k = 0; k < 4; ++k) {
    size_t idx = base + (size_t)k * 256 + t;
    float4 b = t4[idx], m = m4[idx];
    float v0 = b.x * m.x, v1 = b.y * m.y, v2 = b.z * m.z, v3 = b.w * m.w;
    mn = fminf(fminf(fminf(mn, v0), fminf(v1, v2)), v3);
    mx = fmaxf(fmaxf(fmaxf(mx, v0), fmaxf(v1, v2)), v3);
  }

#pragma unroll
  for (int off = 32; off; off >>= 1) {
    mn = fminf(mn, __shfl_down(mn, off));
    mx = fmaxf(mx, __shfl_down(mx, off));
  }
  __shared__ float rmn[4], rmx[4];
  int wave = t >> 6, lane = t & 63;
  if (lane == 0) { rmn[wave] = mn; rmx[wave] = mx; }
  __syncthreads();
  if (t == 0) {
    float MN = fminf(fminf(rmn[0], rmn[1]), fminf(rmn[2], rmn[3]));
    float MX = fmaxf(fmaxf(rmx[0], rmx[1]), fmaxf(rmx[2], rmx[3]));
    atomicMin(&wsu[img], fmap(MN));
    atomicMax(&wsu[48 + img], fmap(MX));
  }
}

// Pass 2: SSIM + fused MAE/MSE. One block per (image, band, column-half):
// 48*22*2 = 2112 blocks of 256 threads. Thread = output column within the
// half. Separable 7x7 box via LDS-staged rows (double-buffered) + 6-deep
// register ring with STATIC slot indices (row loop unrolled by 6).
// Raw-sum algebra: 1/49^2 and 1/(49*48) cancel in the ratio; C1,C2
// pre-scaled by 2401 and 2352.
// MAE/MSE: computed at the LDS-PUBLISH site (registers consumed by ds_write
// anyway -> no extra vmcnt stall), exact-once ownership:
//   rows: bands 0..20 own staged rows 0..22; band 21 owns 0..28.
//   cols: half 0 owns t<253 (not extra); half 1 owns all staged cols.
// Partials -> 64 slotted f64 atomics (chain depth 33).

#define SSIM_ROW(J, ROW, WARM)                                               \
  {                                                                          \
    float nx0 = 0.f, ny0 = 0.f, nx1 = 0.f, ny1 = 0.f;                        \
    const bool pf = (ROW) < BAND_ROWS - 1;                                   \
    if (pf) {                                                                \
      size_t off = rowbase + (size_t)((ROW) + 1) * IMG_W + t;                \
      float m0 = mk[off];                                                    \
      nx0 = yp[off] * m0; ny0 = yt[off] * m0;                                \
      if (extra) {                                                           \
        size_t o2 = off + 256;                                               \
        float m1 = mk[o2];                                                   \
        nx1 = yp[o2] * m1; ny1 = yt[o2] * m1;                                \
      }                                                                      \
    }                                                                        \
    float hx = 0.f, hy = 0.f, hxx = 0.f, hyy = 0.f, hxy = 0.f;               \
    if (prod) {                                                              \
      _Pragma("unroll")                                                      \
      for (int jj = 0; jj < 7; ++jj) {                                       \
        float xv = lx[(J) & 1][t + jj], yv = ly[(J) & 1][t + jj];            \
        hx += xv; hy += yv;                                                  \
        hxx = fmaf(xv, xv, hxx);                                             \
        hyy = fmaf(yv, yv, hyy);                                             \
        hxy = fmaf(xv, yv, hxy);                                             \
      }                                                                      \
    }                                                                        \
    if (!(WARM)) {                                                           \
      float sx = vx_ + hx, sy = vy_ + hy;                                    \
      float sxx = vxx + hxx, syy = vyy + hyy, sxy = vxy + hxy;               \
      if (prod) {                                                            \
        float p = sx * sy;                                                   \
        float q = fmaf(sx, sx, sy * sy);                                     \
        float tt = sxx + syy;                                                \
        float A1 = fmaf(2.f, p, C1q);                                        \
        float A2 = fmaf(-2.f, p, fmaf(98.f, sxy, C2q));                      \
        float B1 = q + C1q;                                                  \
        float B2 = fmaf(49.f, tt, C2q - q);                                  \
        acc = fmaf(A1 * A2, __builtin_amdgcn_rcpf(B1 * B2), acc);            \
      }                                                                      \
      vx_ += hx - rx[(J)]; vy_ += hy - ry[(J)];                              \
      vxx += hxx - rxx[(J)]; vyy += hyy - ryy[(J)]; vxy += hxy - rxy[(J)];   \
    } else {                                                                 \
      vx_ += hx; vy_ += hy; vxx += hxx; vyy += hyy; vxy += hxy;              \
    }                                                                        \
    rx[(J)] = hx; ry[(J)] = hy;                                              \
    rxx[(J)] = hxx; ryy[(J)] = hyy; rxy[(J)] = hxy;                          \
    if (pf) {                                                                \
      lx[1 - ((J) & 1)][t] = nx0; ly[1 - ((J) & 1)][t] = ny0;                \
      if (extra) {                                                           \
        lx[1 - ((J) & 1)][t + 256] = nx1; ly[1 - ((J) & 1)][t + 256] = ny1;  \
      }                                                                      \
      if ((ROW) + 1 <= own_lim) {                                            \
        if (cown) {                                                          \
          float df = nx0 - ny0;                                              \
          bs1 += fabsf(df); bs2 = fmaf(df, df, bs2);                         \
        }                                                                    \
        if (eown) {                                                          \
          float df = nx1 - ny1;                                              \
          bs1 += fabsf(df); bs2 = fmaf(df, df, bs2);                         \
        }                                                                    \
      }                                                                      \
    }                                                                        \
    __syncthreads();                                                         \
  }

__global__ __launch_bounds__(256) void ssim_kernel(
    const float* __restrict__ yp, const float* __restrict__ yt,
    const float* __restrict__ mk, double* __restrict__ wsd,
    const unsigned* __restrict__ wsu) {
  const int bid = blockIdx.x;
  const int img = bid / (2 * N_BANDS);
  const int rem = bid % (2 * N_BANDS);
  const int band = rem >> 1;
  const int half = rem & 1;
  const int c0 = half * HALF_COLS;
  const int r0 = band * BAND_H;
  const size_t rowbase = (size_t)img * IMG_HW + (size_t)r0 * IMG_W + c0;
  const int t = threadIdx.x;
  const bool extra = (t < 3);          // staged cols 256..258 of this half
  const bool prod = (t < HALF_COLS);   // threads producing an output column
  // MAE/MSE ownership
  const int own_lim = (band == N_BANDS - 1) ? (BAND_ROWS - 1) : (BAND_H - 1);
  const bool cown = half || (t < HALF_COLS);
  const bool eown = extra && half;

  const float d = funmap(wsu[48 + img]) - funmap(wsu[img]);
  const float C1q = (K1C * d) * (K1C * d) * 2401.0f;   // C1 * 49^2
  const float C2q = (K2C * d) * (K2C * d) * 2352.0f;   // C2 * 49*48

  __shared__ float lx[2][264];
  __shared__ float ly[2][264];

  float rx[6] = {0,0,0,0,0,0}, ry[6] = {0,0,0,0,0,0};
  float rxx[6] = {0,0,0,0,0,0}, ryy[6] = {0,0,0,0,0,0}, rxy[6] = {0,0,0,0,0,0};
  float vx_ = 0.f, vy_ = 0.f, vxx = 0.f, vyy = 0.f, vxy = 0.f;
  float acc = 0.f, bs1 = 0.f, bs2 = 0.f;

  // stage input row 0 into buffer 0 (row 0 always owned)
  {
    size_t off = rowbase + t;
    float m0 = mk[off];
    float x0 = yp[off] * m0, y0 = yt[off] * m0;
    lx[0][t] = x0; ly[0][t] = y0;
    if (cown) {
      float df = x0 - y0;
      bs1 += fabsf(df); bs2 = fmaf(df, df, bs2);
    }
    if (extra) {
      size_t o2 = off + 256;
      float m1 = mk[o2];
      float x1 = yp[o2] * m1, y1 = yt[o2] * m1;
      lx[0][t + 256] = x1; ly[0][t + 256] = y1;
      if (eown) {
        float df = x1 - y1;
        bs1 += fabsf(df); bs2 = fmaf(df, df, bs2);
      }
    }
  }
  __syncthreads();

  // warm-up rows 0..5 (ring slots 0..5, no output)
  SSIM_ROW(0, 0, true)
  SSIM_ROW(1, 1, true)
  SSIM_ROW(2, 2, true)
  SSIM_ROW(3, 3, true)
  SSIM_ROW(4, 4, true)
  SSIM_ROW(5, 5, true)

  // output rows: input rows 6..23 in three unrolled groups of 6
  for (int g = 0; g < 3; ++g) {
    const int rbase = 6 + 6 * g;
    SSIM_ROW(0, rbase + 0, false)
    SSIM_ROW(1, rbase + 1, false)
    SSIM_ROW(2, rbase + 2, false)
    SSIM_ROW(3, rbase + 3, false)
    SSIM_ROW(4, rbase + 4, false)
    SSIM_ROW(5, rbase + 5, false)
  }
  // tail rows 24..28 (slots 0..4)
  SSIM_ROW(0, 24, false)
  SSIM_ROW(1, 25, false)
  SSIM_ROW(2, 26, false)
  SSIM_ROW(3, 27, false)
  SSIM_ROW(4, 28, false)

  // block reduction -> accumulators
#pragma unroll
  for (int off = 32; off; off >>= 1) {
    acc += __shfl_down(acc, off);
    bs1 += __shfl_down(bs1, off);
    bs2 += __shfl_down(bs2, off);
  }
  __shared__ float warr[4], w1[4], w2[4];
  int wave = t >> 6, lane = t & 63;
  if (lane == 0) { warr[wave] = acc; w1[wave] = bs1; w2[wave] = bs2; }
  __syncthreads();
  if (t == 0) {
    float s = warr[0] + warr[1] + warr[2] + warr[3];
    float a1 = w1[0] + w1[1] + w1[2] + w1[3];
    float a2 = w2[0] + w2[1] + w2[2] + w2[3];
    int slot = bid & 63;
    atomicAdd(&wsd[SLOT_SSIM + img * 2 + (band & 1)], (double)s);
    atomicAdd(&wsd[SLOT_S1 + slot], (double)a1);
    atomicAdd(&wsd[SLOT_S2 + slot], (double)a2);
  }
}

__global__ void finalize_kernel(const double* __restrict__ wsd,
                                float* __restrict__ out) {
  if (threadIdx.x == 0 && blockIdx.x == 0) {
    const double N = (double)N_IMG * (double)IMG_HW;   // 12582912
    double mae = 0.0, mse = 0.0, ssum = 0.0;
    for (int i = 0; i < 64; ++i) { mae += wsd[SLOT_S1 + i]; mse += wsd[SLOT_S2 + i]; }
    mae /= N; mse /= N;
    for (int i = 0; i < 96; ++i) ssum += wsd[SLOT_SSIM + i];
    double smean = ssum / ((double)OUT_W * (double)OUT_H * (double)N_IMG);
    double ssim_loss = 1.0 - smean;
    double total = 1.0 * mae + 0.5 * mse + 0.2 * ssim_loss;
    out[0] = (float)total;
    out[1] = (float)mae;
    out[2] = (float)mse;
    out[3] = (float)ssim_loss;
  }
}

extern "C" void kernel_launch(void* const* d_in, const int* in_sizes, int n_in,
                              void* d_out, int out_size, void* d_ws,
                              size_t ws_size, hipStream_t stream) {
  const float* yp = (const float*)d_in[0];
  const float* yt = (const float*)d_in[1];
  const float* mk = (const float*)d_in[2];
  float* out = (float*)d_out;
  double* wsd = (double*)d_ws;
  unsigned* wsu = (unsigned*)((char*)d_ws + WSU_OFF);

  hipLaunchKernelGGL(init_ws, dim3(1), dim3(256), 0, stream, wsd, wsu);
  hipLaunchKernelGGL(range_kernel, dim3(N_IMG * 64), dim3(256), 0, stream,
                     (const float4*)yt, (const float4*)mk, wsu);
  hipLaunchKernelGGL(ssim_kernel, dim3(N_IMG * N_BANDS * 2), dim3(256), 0,
                     stream, yp, yt, mk, wsd, wsu);
  hipLaunchKernelGGL(finalize_kernel, dim3(1), dim3(64), 0, stream, wsd, out);
}

// Round 6
// 93.884 us; speedup vs baseline: 1.0718x; 1.0718x over previous
//
#include <hip/hip_runtime.h>
#include <math.h>

// Problem geometry
#define N_IMG   48          // B*C = 8*6
#define IMG_W   512
#define IMG_H   512
#define IMG_HW  (IMG_W*IMG_H)
#define OUT_W   506         // 512 - 6 (VALID 7x7)
#define OUT_H   506
#define BAND_H  46          // output rows per band; 46*11 = 506
#define N_BANDS 11
#define HALF_COLS 253       // output columns per half-block
#define K1C     0.01f
#define K2C     0.03f

// ws layout (doubles first, then uints):
//   wsd[0..63]    = sum |diff| partial slots
//   wsd[64..127]  = sum diff^2 partial slots
//   wsd[128..223] = per-image SSIM sums (img*2+half)
//   wsu (byte offset 1792): [0..47] per-image min (ordered map), [48..95] max
#define SLOT_S1   0
#define SLOT_S2   64
#define SLOT_SSIM 128
#define N_DBL     224
#define WSU_OFF   1792

__device__ __forceinline__ unsigned fmap(float f) {
  unsigned u = __float_as_uint(f);
  return (u & 0x80000000u) ? ~u : (u | 0x80000000u);
}
__device__ __forceinline__ float funmap(unsigned u) {
  return (u & 0x80000000u) ? __uint_as_float(u & 0x7FFFFFFFu)
                           : __uint_as_float(~u);
}

__global__ void init_ws(double* wsd, unsigned* wsu) {
  int t = threadIdx.x;
  if (t < N_DBL) wsd[t] = 0.0;
  if (t < 48) { wsu[t] = 0xFFFFFFFFu; wsu[48 + t] = 0u; }
}

// Pass 1: per-image min/max of y_true*mask (reads yt + mk only, 100 MB).
__global__ __launch_bounds__(256) void range_kernel(
    const float4* __restrict__ t4, const float4* __restrict__ m4,
    unsigned* __restrict__ wsu) {
  const int img = blockIdx.x >> 6;
  const int chunk = blockIdx.x & 63;
  const size_t base = (size_t)img * (IMG_HW / 4) + (size_t)chunk * (IMG_HW / 256);
  const int t = threadIdx.x;

  float mn = INFINITY, mx = -INFINITY;
#pragma unroll
  for (int k = 0; k < 4; ++k) {
    size_t idx = base + (size_t)k * 256 + t;
    float4 b = t4[idx], m = m4[idx];
    float v0 = b.x * m.x, v1 = b.y * m.y, v2 = b.z * m.z, v3 = b.w * m.w;
    mn = fminf(fminf(fminf(mn, v0), fminf(v1, v2)), v3);
    mx = fmaxf(fmaxf(fmaxf(mx, v0), fmaxf(v1, v2)), v3);
  }
#pragma unroll
  for (int off = 32; off; off >>= 1) {
    mn = fminf(mn, __shfl_down(mn, off));
    mx = fmaxf(mx, __shfl_down(mx, off));
  }
  __shared__ float rmn[4], rmx[4];
  int wave = t >> 6, lane = t & 63;
  if (lane == 0) { rmn[wave] = mn; rmx[wave] = mx; }
  __syncthreads();
  if (t == 0) {
    float MN = fminf(fminf(rmn[0], rmn[1]), fminf(rmn[2], rmn[3]));
    float MX = fmaxf(fmaxf(rmx[0], rmx[1]), fmaxf(rmx[2], rmx[3]));
    atomicMin(&wsu[img], fmap(MN));
    atomicMax(&wsu[48 + img], fmap(MX));
  }
}

// Pass 2: SSIM + fused MAE/MSE, latency-pipelined.
// 48*11*2 = 1056 blocks of 256 threads. 2 rows per iteration (26 pairs),
// 2-deep pair prefetch: loads for pair p+2 issue at iter p, are written to
// LDS at iter p+1 -> a full iteration of compute hides global-load latency.
// LDS: [pairbuf 2][row 2][264] per array; one barrier per PAIR (27 total).
// Register ring (6 slots, static indices via period-6 macro pattern).
// MAE/MSE computed at the publish site from registers already a full
// iteration old (no latency un-hiding). Exact-once ownership:
//   rows: bands 0..9 own staged rows 0..45; band 10 owns 0..51.
//   cols: half0 owns t<253; half1 owns all its staged cols.

#define LOADP(LS, OFFBASE)                                                    \
  {                                                                          \
    size_t o_ = (OFFBASE) + t;                                               \
    float m0_ = mk[o_];  LS##0x = yp[o_] * m0_;  LS##0y = yt[o_] * m0_;      \
    size_t o1_ = o_ + IMG_W;                                                 \
    float m1_ = mk[o1_]; LS##1x = yp[o1_] * m1_; LS##1y = yt[o1_] * m1_;     \
    if (extra) {                                                             \
      float me0_ = mk[o_ + 256];                                             \
      LS##e0x = yp[o_ + 256] * me0_;  LS##e0y = yt[o_ + 256] * me0_;         \
      float me1_ = mk[o1_ + 256];                                            \
      LS##e1x = yp[o1_ + 256] * me1_; LS##e1y = yt[o1_ + 256] * me1_;        \
    }                                                                        \
  }

#define PUBP(PS, BUFN, OWNF)                                                  \
  {                                                                          \
    lx[BUFN][0][t] = PS##0x; ly[BUFN][0][t] = PS##0y;                        \
    lx[BUFN][1][t] = PS##1x; ly[BUFN][1][t] = PS##1y;                        \
    if (extra) {                                                             \
      lx[BUFN][0][t + 256] = PS##e0x; ly[BUFN][0][t + 256] = PS##e0y;        \
      lx[BUFN][1][t + 256] = PS##e1x; ly[BUFN][1][t + 256] = PS##e1y;        \
    }                                                                        \
    if (OWNF) {                                                              \
      if (cown) {                                                            \
        float d0_ = PS##0x - PS##0y;                                         \
        bs1 += fabsf(d0_); bs2 = fmaf(d0_, d0_, bs2);                        \
        float d1_ = PS##1x - PS##1y;                                         \
        bs1 += fabsf(d1_); bs2 = fmaf(d1_, d1_, bs2);                        \
      }                                                                      \
      if (eown) {                                                            \
        float d0_ = PS##e0x - PS##e0y;                                       \
        bs1 += fabsf(d0_); bs2 = fmaf(d0_, d0_, bs2);                        \
        float d1_ = PS##e1x - PS##e1y;                                       \
        bs1 += fabsf(d1_); bs2 = fmaf(d1_, d1_, bs2);                        \
      }                                                                      \
    }                                                                        \
  }

#define ROWC(BUFC, PAR, SL, WARMF)                                            \
  {                                                                          \
    float hx = 0.f, hy = 0.f, hxx = 0.f, hyy = 0.f, hxy = 0.f;               \
    if (prod) {                                                              \
      _Pragma("unroll")                                                      \
      for (int jj = 0; jj < 7; ++jj) {                                       \
        float xv = lx[BUFC][PAR][t + jj], yv = ly[BUFC][PAR][t + jj];        \
        hx += xv; hy += yv;                                                  \
        hxx = fmaf(xv, xv, hxx);                                             \
        hyy = fmaf(yv, yv, hyy);                                             \
        hxy = fmaf(xv, yv, hxy);                                             \
      }                                                                      \
    }                                                                        \
    if (!(WARMF)) {                                                          \
      float sx = vx_ + hx, sy = vy_ + hy;                                    \
      float sxx = vxx + hxx, syy = vyy + hyy, sxy = vxy + hxy;               \
      if (prod) {                                                            \
        float p_ = sx * sy;                                                  \
        float q_ = fmaf(sx, sx, sy * sy);                                    \
        float tt_ = sxx + syy;                                               \
        float A1_ = fmaf(2.f, p_, C1q);                                      \
        float A2_ = fmaf(-2.f, p_, fmaf(98.f, sxy, C2q));                    \
        float B1_ = q_ + C1q;                                                \
        float B2_ = fmaf(49.f, tt_, C2q - q_);                               \
        acc = fmaf(A1_ * A2_, __builtin_amdgcn_rcpf(B1_ * B2_), acc);        \
      }                                                                      \
      vx_ += hx - rx[SL]; vy_ += hy - ry[SL];                                \
      vxx += hxx - rxx[SL]; vyy += hyy - ryy[SL]; vxy += hxy - rxy[SL];      \
    } else {                                                                 \
      vx_ += hx; vy_ += hy; vxx += hxx; vyy += hyy; vxy += hxy;              \
    }                                                                        \
    rx[SL] = hx; ry[SL] = hy;                                                \
    rxx[SL] = hxx; ryy[SL] = hyy; rxy[SL] = hxy;                             \
  }

// One pipeline iteration p: load pair p+2 -> LS regs; compute pair p from
// LDS buf (BUFC = p&1); publish pair p+1 (PS regs) -> buf 1-BUFC; barrier.
#define ITER(BUFC, SL0, SL1, PS, LS, LOADOFF, DO_LOAD, DO_PUB, WARMF, OWNF)   \
  {                                                                          \
    if (DO_LOAD) LOADP(LS, LOADOFF)                                          \
    ROWC(BUFC, 0, SL0, WARMF)                                                \
    ROWC(BUFC, 1, SL1, WARMF)                                                \
    if (DO_PUB) PUBP(PS, 1 - (BUFC), OWNF)                                   \
    __syncthreads();                                                         \
  }

__global__ __launch_bounds__(256) void ssim_kernel(
    const float* __restrict__ yp, const float* __restrict__ yt,
    const float* __restrict__ mk, double* __restrict__ wsd,
    const unsigned* __restrict__ wsu) {
  const int bid = blockIdx.x;
  const int img = bid / (2 * N_BANDS);
  const int rem = bid % (2 * N_BANDS);
  const int band = rem >> 1;
  const int half = rem & 1;
  const int c0 = half * HALF_COLS;
  const int r0 = band * BAND_H;
  const size_t rowbase = (size_t)img * IMG_HW + (size_t)r0 * IMG_W + c0;
  const int t = threadIdx.x;
  const bool extra = (t < 3);          // staged cols 256..258 of this half
  const bool prod = (t < HALF_COLS);   // produces an output column
  const bool lastband = (band == N_BANDS - 1);
  const bool cown = half || prod;      // main-col MAE ownership
  const bool eown = extra && half;     // extra-col MAE ownership

  const float d = funmap(wsu[48 + img]) - funmap(wsu[img]);
  const float C1q = (K1C * d) * (K1C * d) * 2401.0f;   // C1 * 49^2
  const float C2q = (K2C * d) * (K2C * d) * 2352.0f;   // C2 * 49*48

  __shared__ float lx[2][2][264];
  __shared__ float ly[2][2][264];

  // pair register sets A and B (rows 0/1 of a pair; e* = extra cols)
  float A0x = 0.f, A0y = 0.f, A1x = 0.f, A1y = 0.f;
  float Ae0x = 0.f, Ae0y = 0.f, Ae1x = 0.f, Ae1y = 0.f;
  float B0x = 0.f, B0y = 0.f, B1x = 0.f, B1y = 0.f;
  float Be0x = 0.f, Be0y = 0.f, Be1x = 0.f, Be1y = 0.f;

  float rx[6] = {0,0,0,0,0,0}, ry[6] = {0,0,0,0,0,0};
  float rxx[6] = {0,0,0,0,0,0}, ryy[6] = {0,0,0,0,0,0}, rxy[6] = {0,0,0,0,0,0};
  float vx_ = 0.f, vy_ = 0.f, vxx = 0.f, vyy = 0.f, vxy = 0.f;
  float acc = 0.f, bs1 = 0.f, bs2 = 0.f;

  // Prologue: pair0 (rows 0,1) -> buf0 (+MAE rows 0,1); pair1 (rows 2,3) -> A.
  LOADP(A, rowbase)
  PUBP(A, 0, 1)
  LOADP(A, rowbase + 2 * IMG_W)
  __syncthreads();

  // Warm-up iterations p=0,1,2 (rows 0..5, ring slots 0..5, no output)
  ITER(0, 0, 1, A, B, rowbase + 4 * IMG_W, 1, 1, true, 1)   // p0
  ITER(1, 2, 3, B, A, rowbase + 6 * IMG_W, 1, 1, true, 1)   // p1
  ITER(0, 4, 5, A, B, rowbase + 8 * IMG_W, 1, 1, true, 1)   // p2

  // Steady iterations p=3..20 (3 groups of 6; all published rows <=43 owned)
  for (int g = 0; g < 3; ++g) {
    const size_t lb = rowbase + (size_t)(10 + 12 * g) * IMG_W;
    ITER(1, 0, 1, B, A, lb,               1, 1, false, 1)   // p%6==3
    ITER(0, 2, 3, A, B, lb + 2 * IMG_W,   1, 1, false, 1)   // p%6==4
    ITER(1, 4, 5, B, A, lb + 4 * IMG_W,   1, 1, false, 1)   // p%6==5
    ITER(0, 0, 1, A, B, lb + 6 * IMG_W,   1, 1, false, 1)   // p%6==0
    ITER(1, 2, 3, B, A, lb + 8 * IMG_W,   1, 1, false, 1)   // p%6==1
    ITER(0, 4, 5, A, B, lb + 10 * IMG_W,  1, 1, false, 1)   // p%6==2
  }

  // Tail p=21..25 (published rows 44,45 owned; 46..51 owned iff last band)
  ITER(1, 0, 1, B, A, rowbase + 46 * IMG_W, 1, 1, false, 1)         // p21
  ITER(0, 2, 3, A, B, rowbase + 48 * IMG_W, 1, 1, false, lastband)  // p22
  ITER(1, 4, 5, B, A, rowbase + 50 * IMG_W, 1, 1, false, lastband)  // p23
  ITER(0, 0, 1, A, B, (size_t)0,            0, 1, false, lastband)  // p24
  ITER(1, 2, 3, B, A, (size_t)0,            0, 0, false, 0)         // p25

  // block reduction -> accumulators
#pragma unroll
  for (int off = 32; off; off >>= 1) {
    acc += __shfl_down(acc, off);
    bs1 += __shfl_down(bs1, off);
    bs2 += __shfl_down(bs2, off);
  }
  __shared__ float warr[4], w1s[4], w2s[4];
  int wave = t >> 6, lane = t & 63;
  if (lane == 0) { warr[wave] = acc; w1s[wave] = bs1; w2s[wave] = bs2; }
  __syncthreads();
  if (t == 0) {
    float s = warr[0] + warr[1] + warr[2] + warr[3];
    float a1 = w1s[0] + w1s[1] + w1s[2] + w1s[3];
    float a2 = w2s[0] + w2s[1] + w2s[2] + w2s[3];
    atomicAdd(&wsd[SLOT_SSIM + img * 2 + half], (double)s);   // depth 11
    atomicAdd(&wsd[SLOT_S1 + (bid & 63)], (double)a1);        // depth ~17
    atomicAdd(&wsd[SLOT_S2 + (bid & 63)], (double)a2);
  }
}

__global__ void finalize_kernel(const double* __restrict__ wsd,
                                float* __restrict__ out) {
  if (threadIdx.x == 0 && blockIdx.x == 0) {
    const double N = (double)N_IMG * (double)IMG_HW;   // 12582912
    double mae = 0.0, mse = 0.0, ssum = 0.0;
    for (int i = 0; i < 64; ++i) { mae += wsd[SLOT_S1 + i]; mse += wsd[SLOT_S2 + i]; }
    mae /= N; mse /= N;
    for (int i = 0; i < 96; ++i) ssum += wsd[SLOT_SSIM + i];
    double smean = ssum / ((double)OUT_W * (double)OUT_H * (double)N_IMG);
    double ssim_loss = 1.0 - smean;
    double total = 1.0 * mae + 0.5 * mse + 0.2 * ssim_loss;
    out[0] = (float)total;
    out[1] = (float)mae;
    out[2] = (float)mse;
    out[3] = (float)ssim_loss;
  }
}

extern "C" void kernel_launch(void* const* d_in, const int* in_sizes, int n_in,
                              void* d_out, int out_size, void* d_ws,
                              size_t ws_size, hipStream_t stream) {
  const float* yp = (const float*)d_in[0];
  const float* yt = (const float*)d_in[1];
  const float* mk = (const float*)d_in[2];
  float* out = (float*)d_out;
  double* wsd = (double*)d_ws;
  unsigned* wsu = (unsigned*)((char*)d_ws + WSU_OFF);

  hipLaunchKernelGGL(init_ws, dim3(1), dim3(256), 0, stream, wsd, wsu);
  hipLaunchKernelGGL(range_kernel, dim3(N_IMG * 64), dim3(256), 0, stream,
                     (const float4*)yt, (const float4*)mk, wsu);
  hipLaunchKernelGGL(ssim_kernel, dim3(N_IMG * N_BANDS * 2), dim3(256), 0,
                     stream, yp, yt, mk, wsd, wsu);
  hipLaunchKernelGGL(finalize_kernel, dim3(1), dim3(64), 0, stream, wsd, out);
}